// Round 1
// baseline (251.574 us; speedup 1.0000x reference)
//
#include <hip/hip_runtime.h>
#include <hip/hip_bf16.h>

// Problem constants (B=32, N=256, K=20, channels 3->64->128->256, fc 256->128->40)
#define B_ 32
#define N_ 256
#define K_ 20
#define C1 64
#define C2 128
#define C3 256
#define F1 128
#define F2 40
#define NEG_INF (-3.402823466e38f)

// ---------------------------------------------------------------------------
// Kernel 1: per-(b,n) pairwise distance + top-20 neighbor indices.
// pairwise[n][m] = 2*dot(xn,xm) - ||xn||^2 - ||xm||^2  (== -||xn-xm||^2)
// Iterative argmax x20 with tie-break to LOWER index (matches lax.top_k).
// ---------------------------------------------------------------------------
__global__ __launch_bounds__(256) void k_topk(const float* __restrict__ x,
                                              int* __restrict__ idx) {
    const int bn = blockIdx.x;          // b*256 + n
    const int b  = bn >> 8;
    const int n  = bn & 255;
    const int t  = threadIdx.x;

    __shared__ float xs[N_ * 3];
    __shared__ float xxs[N_];
    __shared__ float wv[4];
    __shared__ int   wi[4];
    __shared__ int   winner;

    const float* xb = x + (size_t)b * N_ * 3;
    for (int e = t; e < N_ * 3; e += 256) xs[e] = xb[e];
    __syncthreads();

    const float x0 = xs[t * 3 + 0], x1 = xs[t * 3 + 1], x2 = xs[t * 3 + 2];
    const float xx = x0 * x0 + x1 * x1 + x2 * x2;
    xxs[t] = xx;
    __syncthreads();

    const float n0 = xs[n * 3 + 0], n1 = xs[n * 3 + 1], n2 = xs[n * 3 + 2];
    const float xxn = xxs[n];
    const float dot = n0 * x0 + n1 * x1 + n2 * x2;
    float v = 2.0f * dot - xxn - xx;    // self (t==n) is exactly 0.0f, the max

    const int lane = t & 63;
    const int wave = t >> 6;
    int* out = idx + (size_t)bn * K_;

    for (int it = 0; it < K_; ++it) {
        float rv = v;
        int   ri = t;
        #pragma unroll
        for (int s = 32; s > 0; s >>= 1) {
            float ov = __shfl_down(rv, s, 64);
            int   oi = __shfl_down(ri, s, 64);
            if (ov > rv || (ov == rv && oi < ri)) { rv = ov; ri = oi; }
        }
        if (lane == 0) { wv[wave] = rv; wi[wave] = ri; }
        __syncthreads();
        if (t == 0) {
            float bv = wv[0]; int bi = wi[0];
            #pragma unroll
            for (int w = 1; w < 4; ++w)
                if (wv[w] > bv || (wv[w] == bv && wi[w] < bi)) { bv = wv[w]; bi = wi[w]; }
            winner = bi;
            out[it] = bi;
        }
        __syncthreads();
        if (t == winner) v = NEG_INF;   // knock out for next round
    }
}

// ---------------------------------------------------------------------------
// Kernel 2: per-POINT MLP 3->64->128->256 (relu + folded-BN affine each layer).
// Exploits that the "graph feature" is just the neighbor's own coords, so the
// MLP is computed once per point (8192) instead of once per neighbor (163840).
// 16 points per block; activations kept LDS-transposed [chan][point] so the
// inner loops are wave-broadcast contiguous reads.
// ---------------------------------------------------------------------------
__global__ __launch_bounds__(256) void k_mlp(const float* __restrict__ x,
                                             const float* __restrict__ w1,
                                             const float* __restrict__ s1,
                                             const float* __restrict__ b1,
                                             const float* __restrict__ w2,
                                             const float* __restrict__ s2,
                                             const float* __restrict__ b2,
                                             const float* __restrict__ w3,
                                             const float* __restrict__ s3,
                                             const float* __restrict__ b3,
                                             float* __restrict__ P) {
    const int tid   = threadIdx.x;
    const int pbase = blockIdx.x * 16;  // global point index base

    __shared__ float xs[16 * 3];
    __shared__ float y1t[C1 * 16];      // [c1][p]
    __shared__ float y2t[C2 * 16];      // [c2][p]

    if (tid < 48) xs[tid] = x[(size_t)pbase * 3 + tid];
    __syncthreads();

    // ---- layer 1: 64 x 3 ----
    {
        const int o = tid & 63;
        const int q = tid >> 6;         // quarter: handles 4 points
        const float wa = w1[o * 3 + 0], wb = w1[o * 3 + 1], wc = w1[o * 3 + 2];
        const float sc = s1[o], sh = b1[o];
        #pragma unroll
        for (int i = 0; i < 4; ++i) {
            const int p = q * 4 + i;
            float vv = wa * xs[p * 3 + 0] + wb * xs[p * 3 + 1] + wc * xs[p * 3 + 2];
            y1t[o * 16 + p] = fmaxf(vv * sc + sh, 0.0f);
        }
    }
    __syncthreads();

    // ---- layer 2: 128 x 64 ----
    {
        const int o = tid & 127;
        const int h = (tid >> 7) * 8;   // point half: 8 points
        float acc[8] = {0, 0, 0, 0, 0, 0, 0, 0};
        const float4* wrow = (const float4*)(w2 + (size_t)o * C1);
        for (int c = 0; c < C1; c += 4) {
            float4 w4 = wrow[c >> 2];
            #pragma unroll
            for (int cc = 0; cc < 4; ++cc) {
                const float wcc = (&w4.x)[cc];
                const float* yp = y1t + (c + cc) * 16 + h;
                #pragma unroll
                for (int p = 0; p < 8; ++p) acc[p] += wcc * yp[p];
            }
        }
        const float sc = s2[o], sh = b2[o];
        #pragma unroll
        for (int p = 0; p < 8; ++p)
            y2t[o * 16 + h + p] = fmaxf(acc[p] * sc + sh, 0.0f);
    }
    __syncthreads();

    // ---- layer 3: 256 x 128 ----
    {
        const int o = tid;
        float acc[16];
        #pragma unroll
        for (int p = 0; p < 16; ++p) acc[p] = 0.0f;
        const float4* wrow = (const float4*)(w3 + (size_t)o * C2);
        for (int c = 0; c < C2; c += 4) {
            float4 w4 = wrow[c >> 2];
            #pragma unroll
            for (int cc = 0; cc < 4; ++cc) {
                const float wcc = (&w4.x)[cc];
                const float* yp = y2t + (c + cc) * 16;
                #pragma unroll
                for (int p = 0; p < 16; ++p) acc[p] += wcc * yp[p];
            }
        }
        const float sc = s3[o], sh = b3[o];
        #pragma unroll
        for (int p = 0; p < 16; ++p) {
            float vv = fmaxf(acc[p] * sc + sh, 0.0f);
            P[(size_t)(pbase + p) * C3 + o] = vv;   // P[point][chan], coalesced
        }
    }
}

// ---------------------------------------------------------------------------
// Kernel 3: gather-max over the 20 neighbors. H[b][n][c] = max_j P[b, idx_j, c]
// ---------------------------------------------------------------------------
__global__ __launch_bounds__(256) void k_gmax(const float* __restrict__ P,
                                              const int* __restrict__ idx,
                                              float* __restrict__ H) {
    const int bn = blockIdx.x;
    const int b  = bn >> 8;
    const int t  = threadIdx.x;
    __shared__ int id[K_];
    if (t < K_) id[t] = idx[(size_t)bn * K_ + t];
    __syncthreads();
    const float* Pb = P + (size_t)b * N_ * C3;
    float m = NEG_INF;
    #pragma unroll
    for (int j = 0; j < K_; ++j)
        m = fmaxf(m, Pb[(size_t)id[j] * C3 + t]);
    H[(size_t)bn * C3 + t] = m;
}

// ---------------------------------------------------------------------------
// Kernel 4: fused fc1(relu) + fc2 over the point axis.
// out[b][c][m] = sum_j relu(sum_n H[b][n][c]*fc1w[j][n] + fc1b[j]) * fc2w[m][j] + fc2b[m]
// One block per (b, 16-channel tile). LDS strides padded (17/129) vs bank=32.
// ---------------------------------------------------------------------------
__global__ __launch_bounds__(256) void k_fc(const float* __restrict__ H,
                                            const float* __restrict__ fc1w,
                                            const float* __restrict__ fc1b,
                                            const float* __restrict__ fc2w,
                                            const float* __restrict__ fc2b,
                                            float* __restrict__ out) {
    const int b  = blockIdx.x >> 4;
    const int c0 = (blockIdx.x & 15) * 16;
    const int t  = threadIdx.x;

    __shared__ float Ht[N_ * 16];        // [n][ci], stride 16 (reads are broadcast)
    __shared__ float gl[F1 * 17];        // [j][ci], padded
    __shared__ float w2l[F2 * 129];      // [m][j], padded
    __shared__ float b1l[F1];
    __shared__ float b2l[F2];

    const float* Hb = H + (size_t)b * N_ * C3;
    for (int e = t; e < N_ * 16; e += 256) {
        const int n = e >> 4, ci = e & 15;
        Ht[e] = Hb[(size_t)n * C3 + c0 + ci];
    }
    for (int e = t; e < F2 * F1; e += 256)
        w2l[(e >> 7) * 129 + (e & 127)] = fc2w[e];
    if (t < F1) b1l[t] = fc1b[t];
    if (t < F2) b2l[t] = fc2b[t];
    __syncthreads();

    // fc1 + relu -> gl[j][ci]
    {
        const int j = t & 127;
        const int h = (t >> 7) * 8;     // channel half within tile
        float acc[8] = {0, 0, 0, 0, 0, 0, 0, 0};
        const float4* wrow = (const float4*)(fc1w + (size_t)j * N_);
        for (int n = 0; n < N_; n += 4) {
            float4 w4 = wrow[n >> 2];
            #pragma unroll
            for (int nn = 0; nn < 4; ++nn) {
                const float wc = (&w4.x)[nn];
                const float* hp = Ht + (n + nn) * 16 + h;
                #pragma unroll
                for (int i = 0; i < 8; ++i) acc[i] += wc * hp[i];
            }
        }
        const float bj = b1l[j];
        #pragma unroll
        for (int i = 0; i < 8; ++i)
            gl[j * 17 + h + i] = fmaxf(acc[i] + bj, 0.0f);
    }
    __syncthreads();

    // fc2 -> out
    for (int e = t; e < 16 * F2; e += 256) {
        const int ci = e / F2;
        const int m  = e % F2;
        float acc = b2l[m];
        const float* wr = w2l + m * 129;
        for (int j = 0; j < F1; ++j)
            acc += wr[j] * gl[j * 17 + ci];
        out[((size_t)(b * C3 + c0 + ci)) * F2 + m] = acc;
    }
}

// ---------------------------------------------------------------------------
extern "C" void kernel_launch(void* const* d_in, const int* in_sizes, int n_in,
                              void* d_out, int out_size, void* d_ws, size_t ws_size,
                              hipStream_t stream) {
    const float* x    = (const float*)d_in[0];
    const float* w1   = (const float*)d_in[1];
    const float* s1   = (const float*)d_in[2];
    const float* t1   = (const float*)d_in[3];
    const float* w2   = (const float*)d_in[4];
    const float* s2   = (const float*)d_in[5];
    const float* t2   = (const float*)d_in[6];
    const float* w3   = (const float*)d_in[7];
    const float* s3   = (const float*)d_in[8];
    const float* t3   = (const float*)d_in[9];
    const float* fc1w = (const float*)d_in[10];
    const float* fc1b = (const float*)d_in[11];
    const float* fc2w = (const float*)d_in[12];
    const float* fc2b = (const float*)d_in[13];
    float* out = (float*)d_out;

    // Workspace layout (all fully overwritten every call):
    //   idx: B*N*K ints   = 655,360 B
    //   P:   B*N*C3 float = 8,388,608 B
    //   H:   B*N*C3 float = 8,388,608 B
    char* ws = (char*)d_ws;
    int*   idx = (int*)ws;
    float* P   = (float*)(ws + (size_t)B_ * N_ * K_ * 4);
    float* H   = P + (size_t)B_ * N_ * C3;

    k_topk<<<B_ * N_, 256, 0, stream>>>(x, idx);
    k_mlp <<<(B_ * N_) / 16, 256, 0, stream>>>(x, w1, s1, t1, w2, s2, t2,
                                               w3, s3, t3, P);
    k_gmax<<<B_ * N_, 256, 0, stream>>>(P, idx, H);
    k_fc  <<<B_ * 16, 256, 0, stream>>>(H, fc1w, fc1b, fc2w, fc2b, out);
}

// Round 2
// 167.022 us; speedup vs baseline: 1.5062x; 1.5062x over previous
//
#include <hip/hip_runtime.h>
#include <hip/hip_bf16.h>

// Problem constants (B=32, N=256, K=20, channels 3->64->128->256, fc 256->128->40)
#define B_ 32
#define N_ 256
#define K_ 20
#define C1 64
#define C2 128
#define C3 256
#define F1 128
#define F2 40
#define NEG_INF (-3.402823466e38f)

// ---------------------------------------------------------------------------
// Kernel 1: per-point top-20 neighbors, ONE WAVE PER POINT, no barriers in the
// selection loop. Each lane owns 4 of the 256 candidates. Candidate keys are
// packed u64: (monotone(f32 bits) << 8) | (255 - index), so max + tie-break-
// to-lowest-index is one unsigned compare. Value comparison remains exact f32.
// pairwise[n][m] = 2*dot(xn,xm) - ||xn||^2 - ||xm||^2 (== -||xn-xm||^2).
// ---------------------------------------------------------------------------
__global__ __launch_bounds__(256) void k_topk(const float* __restrict__ x,
                                              int* __restrict__ idx) {
    const int t    = threadIdx.x;
    const int lane = t & 63;
    const int wave = t >> 6;
    const int b    = blockIdx.x >> 6;             // 64 blocks per batch
    const int n    = ((blockIdx.x & 63) << 2) | wave;
    const int bn   = (b << 8) | n;

    __shared__ float xs[N_ * 3];
    __shared__ float xxs[N_];

    const float* xb = x + (size_t)b * N_ * 3;
    for (int e = t; e < N_ * 3; e += 256) xs[e] = xb[e];
    __syncthreads();
    {
        const float a0 = xs[t * 3 + 0], a1 = xs[t * 3 + 1], a2 = xs[t * 3 + 2];
        xxs[t] = a0 * a0 + a1 * a1 + a2 * a2;
    }
    __syncthreads();

    const float nx = xs[n * 3 + 0], ny = xs[n * 3 + 1], nz = xs[n * 3 + 2];
    const float xxn = xxs[n];

    unsigned long long k0, k1, k2, k3;
    {
        unsigned long long kk[4];
        #pragma unroll
        for (int i = 0; i < 4; ++i) {
            const int m = lane + (i << 6);
            const float cx = xs[m * 3 + 0], cy = xs[m * 3 + 1], cz = xs[m * 3 + 2];
            const float v = 2.0f * (nx * cx + ny * cy + nz * cz) - xxn - xxs[m];
            unsigned u = __float_as_uint(v);
            unsigned key32 = (u & 0x80000000u) ? ~u : (u | 0x80000000u);
            kk[i] = ((unsigned long long)key32 << 8) | (unsigned)(255 - m);
        }
        k0 = kk[0]; k1 = kk[1]; k2 = kk[2]; k3 = kk[3];
    }

    int mine = 0;
    #pragma unroll 1
    for (int it = 0; it < K_; ++it) {
        unsigned long long ra = (k0 > k1) ? k0 : k1;
        unsigned long long rb = (k2 > k3) ? k2 : k3;
        unsigned long long rk = (ra > rb) ? ra : rb;
        #pragma unroll
        for (int s = 1; s < 64; s <<= 1) {
            unsigned long long ok = __shfl_xor(rk, s, 64);
            if (ok > rk) rk = ok;
        }
        const int ri = 255 - (int)(rk & 0xFFull);   // winner candidate index
        if (lane == it) mine = ri;
        // knock out winner for the next round
        if (lane == (ri & 63)) {
            const int slot = ri >> 6;
            if      (slot == 0) k0 = 0ull;
            else if (slot == 1) k1 = 0ull;
            else if (slot == 2) k2 = 0ull;
            else                k3 = 0ull;
        }
    }
    if (lane < K_) idx[(size_t)bn * K_ + lane] = mine;
}

// ---------------------------------------------------------------------------
// Kernel 2: per-POINT MLP 3->64->128->256 (relu + folded-BN affine each layer).
// The "graph feature" is just the neighbor's own coords, so the MLP is
// computed once per point (8192) instead of once per neighbor (163840).
// 16 points per block; activations LDS-transposed [chan][point].
// ---------------------------------------------------------------------------
__global__ __launch_bounds__(256) void k_mlp(const float* __restrict__ x,
                                             const float* __restrict__ w1,
                                             const float* __restrict__ s1,
                                             const float* __restrict__ b1,
                                             const float* __restrict__ w2,
                                             const float* __restrict__ s2,
                                             const float* __restrict__ b2,
                                             const float* __restrict__ w3,
                                             const float* __restrict__ s3,
                                             const float* __restrict__ b3,
                                             float* __restrict__ P) {
    const int tid   = threadIdx.x;
    const int pbase = blockIdx.x * 16;  // global point index base

    __shared__ float xs[16 * 3];
    __shared__ float y1t[C1 * 16];      // [c1][p]
    __shared__ float y2t[C2 * 16];      // [c2][p]

    if (tid < 48) xs[tid] = x[(size_t)pbase * 3 + tid];
    __syncthreads();

    // ---- layer 1: 64 x 3 ----
    {
        const int o = tid & 63;
        const int q = tid >> 6;         // quarter: handles 4 points
        const float wa = w1[o * 3 + 0], wb = w1[o * 3 + 1], wc = w1[o * 3 + 2];
        const float sc = s1[o], sh = b1[o];
        #pragma unroll
        for (int i = 0; i < 4; ++i) {
            const int p = q * 4 + i;
            float vv = wa * xs[p * 3 + 0] + wb * xs[p * 3 + 1] + wc * xs[p * 3 + 2];
            y1t[o * 16 + p] = fmaxf(vv * sc + sh, 0.0f);
        }
    }
    __syncthreads();

    // ---- layer 2: 128 x 64 ----
    {
        const int o = tid & 127;
        const int h = (tid >> 7) * 8;   // point half: 8 points
        float acc[8] = {0, 0, 0, 0, 0, 0, 0, 0};
        const float4* wrow = (const float4*)(w2 + (size_t)o * C1);
        for (int c = 0; c < C1; c += 4) {
            float4 w4 = wrow[c >> 2];
            #pragma unroll
            for (int cc = 0; cc < 4; ++cc) {
                const float wcc = (&w4.x)[cc];
                const float* yp = y1t + (c + cc) * 16 + h;
                #pragma unroll
                for (int p = 0; p < 8; ++p) acc[p] += wcc * yp[p];
            }
        }
        const float sc = s2[o], sh = b2[o];
        #pragma unroll
        for (int p = 0; p < 8; ++p)
            y2t[o * 16 + h + p] = fmaxf(acc[p] * sc + sh, 0.0f);
    }
    __syncthreads();

    // ---- layer 3: 256 x 128 ----
    {
        const int o = tid;
        float acc[16];
        #pragma unroll
        for (int p = 0; p < 16; ++p) acc[p] = 0.0f;
        const float4* wrow = (const float4*)(w3 + (size_t)o * C2);
        for (int c = 0; c < C2; c += 4) {
            float4 w4 = wrow[c >> 2];
            #pragma unroll
            for (int cc = 0; cc < 4; ++cc) {
                const float wcc = (&w4.x)[cc];
                const float* yp = y2t + (c + cc) * 16;
                #pragma unroll
                for (int p = 0; p < 16; ++p) acc[p] += wcc * yp[p];
            }
        }
        const float sc = s3[o], sh = b3[o];
        #pragma unroll
        for (int p = 0; p < 16; ++p) {
            float vv = fmaxf(acc[p] * sc + sh, 0.0f);
            P[(size_t)(pbase + p) * C3 + o] = vv;   // P[point][chan], coalesced
        }
    }
}

// ---------------------------------------------------------------------------
// Kernel 3: gather-max over the 20 neighbors, one wave per (b,n) row.
// Lane l owns channels 4l..4l+3 (float4). 20 coalesced 1 KB row reads.
// ---------------------------------------------------------------------------
__global__ __launch_bounds__(256) void k_gmax(const float* __restrict__ P,
                                              const int* __restrict__ idx,
                                              float* __restrict__ H) {
    const int t    = threadIdx.x;
    const int lane = t & 63;
    const int bn   = blockIdx.x * 4 + (t >> 6);
    const int b    = bn >> 8;

    const float* Pb = P + (size_t)b * N_ * C3;
    const int*   ib = idx + (size_t)bn * K_;

    float4 m = make_float4(NEG_INF, NEG_INF, NEG_INF, NEG_INF);
    #pragma unroll
    for (int j = 0; j < K_; ++j) {
        const int id = ib[j];                       // wave-uniform broadcast
        const float4 p = ((const float4*)(Pb + (size_t)id * C3))[lane];
        m.x = fmaxf(m.x, p.x);
        m.y = fmaxf(m.y, p.y);
        m.z = fmaxf(m.z, p.z);
        m.w = fmaxf(m.w, p.w);
    }
    ((float4*)(H + (size_t)bn * C3))[lane] = m;
}

// ---------------------------------------------------------------------------
// Kernel 4: fused fc1(relu) + fc2 over the point axis.
// One block per (b, 16-channel tile). LDS strides padded (17/129) vs bank=32.
// ---------------------------------------------------------------------------
__global__ __launch_bounds__(256) void k_fc(const float* __restrict__ H,
                                            const float* __restrict__ fc1w,
                                            const float* __restrict__ fc1b,
                                            const float* __restrict__ fc2w,
                                            const float* __restrict__ fc2b,
                                            float* __restrict__ out) {
    const int b  = blockIdx.x >> 4;
    const int c0 = (blockIdx.x & 15) * 16;
    const int t  = threadIdx.x;

    __shared__ float Ht[N_ * 16];        // [n][ci]
    __shared__ float gl[F1 * 17];        // [j][ci], padded
    __shared__ float w2l[F2 * 129];      // [m][j], padded
    __shared__ float b1l[F1];
    __shared__ float b2l[F2];

    const float* Hb = H + (size_t)b * N_ * C3;
    for (int e = t; e < N_ * 16; e += 256) {
        const int n = e >> 4, ci = e & 15;
        Ht[e] = Hb[(size_t)n * C3 + c0 + ci];
    }
    for (int e = t; e < F2 * F1; e += 256)
        w2l[(e >> 7) * 129 + (e & 127)] = fc2w[e];
    if (t < F1) b1l[t] = fc1b[t];
    if (t < F2) b2l[t] = fc2b[t];
    __syncthreads();

    // fc1 + relu -> gl[j][ci]
    {
        const int j = t & 127;
        const int h = (t >> 7) * 8;     // channel half within tile
        float acc[8] = {0, 0, 0, 0, 0, 0, 0, 0};
        const float4* wrow = (const float4*)(fc1w + (size_t)j * N_);
        for (int n = 0; n < N_; n += 4) {
            float4 w4 = wrow[n >> 2];
            #pragma unroll
            for (int nn = 0; nn < 4; ++nn) {
                const float wc = (&w4.x)[nn];
                const float* hp = Ht + (n + nn) * 16 + h;
                #pragma unroll
                for (int i = 0; i < 8; ++i) acc[i] += wc * hp[i];
            }
        }
        const float bj = b1l[j];
        #pragma unroll
        for (int i = 0; i < 8; ++i)
            gl[j * 17 + h + i] = fmaxf(acc[i] + bj, 0.0f);
    }
    __syncthreads();

    // fc2 -> out
    for (int e = t; e < 16 * F2; e += 256) {
        const int ci = e / F2;
        const int m  = e % F2;
        float acc = b2l[m];
        const float* wr = w2l + m * 129;
        for (int j = 0; j < F1; ++j)
            acc += wr[j] * gl[j * 17 + ci];
        out[((size_t)(b * C3 + c0 + ci)) * F2 + m] = acc;
    }
}

// ---------------------------------------------------------------------------
extern "C" void kernel_launch(void* const* d_in, const int* in_sizes, int n_in,
                              void* d_out, int out_size, void* d_ws, size_t ws_size,
                              hipStream_t stream) {
    const float* x    = (const float*)d_in[0];
    const float* w1   = (const float*)d_in[1];
    const float* s1   = (const float*)d_in[2];
    const float* t1   = (const float*)d_in[3];
    const float* w2   = (const float*)d_in[4];
    const float* s2   = (const float*)d_in[5];
    const float* t2   = (const float*)d_in[6];
    const float* w3   = (const float*)d_in[7];
    const float* s3   = (const float*)d_in[8];
    const float* t3   = (const float*)d_in[9];
    const float* fc1w = (const float*)d_in[10];
    const float* fc1b = (const float*)d_in[11];
    const float* fc2w = (const float*)d_in[12];
    const float* fc2b = (const float*)d_in[13];
    float* out = (float*)d_out;

    // Workspace layout (all fully overwritten every call):
    //   idx: B*N*K ints   = 655,360 B
    //   P:   B*N*C3 float = 8,388,608 B
    //   H:   B*N*C3 float = 8,388,608 B
    char* ws = (char*)d_ws;
    int*   idx = (int*)ws;
    float* P   = (float*)(ws + (size_t)B_ * N_ * K_ * 4);
    float* H   = P + (size_t)B_ * N_ * C3;

    k_topk<<<(B_ * N_) / 4, 256, 0, stream>>>(x, idx);
    k_mlp <<<(B_ * N_) / 16, 256, 0, stream>>>(x, w1, s1, t1, w2, s2, t2,
                                               w3, s3, t3, P);
    k_gmax<<<(B_ * N_) / 4, 256, 0, stream>>>(P, idx, H);
    k_fc  <<<B_ * 16, 256, 0, stream>>>(H, fc1w, fc1b, fc2w, fc2b, out);
}

// Round 3
// 164.599 us; speedup vs baseline: 1.5284x; 1.0147x over previous
//
#include <hip/hip_runtime.h>
#include <hip/hip_bf16.h>

// Problem constants (B=32, N=256, K=20, channels 3->64->128->256, fc 256->128->40)
#define B_ 32
#define N_ 256
#define K_ 20
#define C1 64
#define C2 128
#define C3 256
#define F1 128
#define F2 40
#define NEG_INF (-3.402823466e38f)

// ---------------------------------------------------------------------------
// Stage 1 (merged launch): blocks [0,256) run the per-point MLP (32 pts/block);
// blocks [256, 2304) run per-point top-20 (one wave per point). The two are
// independent (both read only x) and overlap across CUs. MLP blocks first so
// they start while topk blocks stream through.
// ---------------------------------------------------------------------------
__global__ __launch_bounds__(256) void k_stage1(const float* __restrict__ x,
    const float* __restrict__ w1, const float* __restrict__ s1, const float* __restrict__ b1,
    const float* __restrict__ w2, const float* __restrict__ s2, const float* __restrict__ b2,
    const float* __restrict__ w3, const float* __restrict__ s3, const float* __restrict__ b3,
    int* __restrict__ idx, float* __restrict__ P) {
    const int t = threadIdx.x;

    if (blockIdx.x >= 256) {
        // ---------------- top-20, one wave per point ----------------
        __shared__ float xs[N_ * 3];
        __shared__ float xxs[N_];
        const int blk  = blockIdx.x - 256;
        const int lane = t & 63;
        const int wave = t >> 6;
        const int b    = blk >> 6;
        const int n    = ((blk & 63) << 2) | wave;
        const int bn   = (b << 8) | n;

        const float* xb = x + (size_t)b * N_ * 3;
        for (int e = t; e < N_ * 3; e += 256) xs[e] = xb[e];
        __syncthreads();
        {
            const float a0 = xs[t * 3 + 0], a1 = xs[t * 3 + 1], a2 = xs[t * 3 + 2];
            xxs[t] = a0 * a0 + a1 * a1 + a2 * a2;
        }
        __syncthreads();

        const float nx = xs[n * 3 + 0], ny = xs[n * 3 + 1], nz = xs[n * 3 + 2];
        const float xxn = xxs[n];

        unsigned long long k0, k1, k2, k3;
        {
            unsigned long long kk[4];
            #pragma unroll
            for (int i = 0; i < 4; ++i) {
                const int m = lane + (i << 6);
                const float cx = xs[m * 3 + 0], cy = xs[m * 3 + 1], cz = xs[m * 3 + 2];
                const float v = 2.0f * (nx * cx + ny * cy + nz * cz) - xxn - xxs[m];
                unsigned u = __float_as_uint(v);
                unsigned key32 = (u & 0x80000000u) ? ~u : (u | 0x80000000u);
                kk[i] = ((unsigned long long)key32 << 8) | (unsigned)(255 - m);
            }
            k0 = kk[0]; k1 = kk[1]; k2 = kk[2]; k3 = kk[3];
        }

        int mine = 0;
        #pragma unroll 1
        for (int it = 0; it < K_; ++it) {
            unsigned long long ra = (k0 > k1) ? k0 : k1;
            unsigned long long rb = (k2 > k3) ? k2 : k3;
            unsigned long long rk = (ra > rb) ? ra : rb;
            #pragma unroll
            for (int s = 1; s < 64; s <<= 1) {
                unsigned long long ok = __shfl_xor(rk, s, 64);
                if (ok > rk) rk = ok;
            }
            const int ri = 255 - (int)(rk & 0xFFull);
            if (lane == it) mine = ri;
            if (lane == (ri & 63)) {
                const int slot = ri >> 6;
                if      (slot == 0) k0 = 0ull;
                else if (slot == 1) k1 = 0ull;
                else if (slot == 2) k2 = 0ull;
                else                k3 = 0ull;
            }
        }
        if (lane < K_) idx[(size_t)bn * K_ + lane] = mine;

    } else {
        // ---------------- per-point MLP, 32 points/block ----------------
        __shared__ float mxs[32 * 3];
        __shared__ float y1t[C1 * 32];      // [c1][p], stride 32
        __shared__ float y2t[C2 * 32];      // [c2][p], stride 32
        const int pbase = blockIdx.x * 32;

        if (t < 96) mxs[t] = x[(size_t)pbase * 3 + t];
        __syncthreads();

        // ---- layer 1: 64 x 3 -> thread = (oc, 8-pt group) ----
        {
            const int oc = t >> 2, p0 = (t & 3) * 8;
            const float wa = w1[oc * 3 + 0], wb = w1[oc * 3 + 1], wc = w1[oc * 3 + 2];
            const float sc = s1[oc], sh = b1[oc];
            float o[8];
            #pragma unroll
            for (int p = 0; p < 8; ++p) {
                const int pp = p0 + p;
                float v = wa * mxs[pp * 3 + 0] + wb * mxs[pp * 3 + 1] + wc * mxs[pp * 3 + 2];
                o[p] = fmaxf(v * sc + sh, 0.0f);
            }
            *(float4*)&y1t[oc * 32 + p0]     = make_float4(o[0], o[1], o[2], o[3]);
            *(float4*)&y1t[oc * 32 + p0 + 4] = make_float4(o[4], o[5], o[6], o[7]);
        }
        __syncthreads();

        // ---- layer 2: 128 x 64, tile 4oc x 4pt ----
        {
            const int oc0 = (t >> 3) * 4, p0 = (t & 7) * 4;
            float acc[4][4] = {};
            for (int k = 0; k < C1; k += 4) {
                float4 y[4], w[4];
                #pragma unroll
                for (int i = 0; i < 4; ++i) y[i] = *(const float4*)&y1t[(k + i) * 32 + p0];
                #pragma unroll
                for (int i = 0; i < 4; ++i) w[i] = *(const float4*)&w2[(oc0 + i) * C1 + k];
                #pragma unroll
                for (int o = 0; o < 4; ++o) {
                    #pragma unroll
                    for (int kk = 0; kk < 4; ++kk) {
                        const float wv = (&w[o].x)[kk];
                        #pragma unroll
                        for (int p = 0; p < 4; ++p) acc[o][p] += wv * (&y[kk].x)[p];
                    }
                }
            }
            #pragma unroll
            for (int o = 0; o < 4; ++o) {
                const int oc = oc0 + o;
                const float sc = s2[oc], sh = b2[oc];
                float4 v;
                #pragma unroll
                for (int p = 0; p < 4; ++p) (&v.x)[p] = fmaxf(acc[o][p] * sc + sh, 0.0f);
                *(float4*)&y2t[oc * 32 + p0] = v;
            }
        }
        __syncthreads();

        // ---- layer 3: 256 x 128, tile 8oc x 8pt, k split in halves,
        //      merged via shfl_xor(4) (partner = same wave) ----
        {
            const int p0  = (t & 3) * 8;
            const int kh  = (t >> 2) & 1;
            const int oc0 = (t >> 3) * 8;
            const int kbase = kh * 64;
            float acc[8][8] = {};
            for (int kg = 0; kg < 16; ++kg) {
                const int k = kbase + kg * 4;
                float4 ya[4], yb[4], w[8];
                #pragma unroll
                for (int i = 0; i < 4; ++i) {
                    ya[i] = *(const float4*)&y2t[(k + i) * 32 + p0];
                    yb[i] = *(const float4*)&y2t[(k + i) * 32 + p0 + 4];
                }
                #pragma unroll
                for (int o = 0; o < 8; ++o) w[o] = *(const float4*)&w3[(oc0 + o) * C2 + k];
                #pragma unroll
                for (int o = 0; o < 8; ++o) {
                    #pragma unroll
                    for (int i = 0; i < 4; ++i) {
                        const float wv = (&w[o].x)[i];
                        #pragma unroll
                        for (int p = 0; p < 4; ++p) {
                            acc[o][p]     += wv * (&ya[i].x)[p];
                            acc[o][p + 4] += wv * (&yb[i].x)[p];
                        }
                    }
                }
            }
            // k-half merge: both partners end with the full sum
            #pragma unroll
            for (int o = 0; o < 8; ++o)
                #pragma unroll
                for (int p = 0; p < 8; ++p)
                    acc[o][p] += __shfl_xor(acc[o][p], 4, 64);
            // epilogue: each partner writes its 4-oc half
            const int ocw = oc0 + kh * 4;
            #pragma unroll
            for (int p = 0; p < 8; ++p) {
                float4 v;
                #pragma unroll
                for (int q = 0; q < 4; ++q) {
                    const int oc = ocw + q;
                    (&v.x)[q] = fmaxf(acc[kh * 4 + q][p] * s3[oc] + b3[oc], 0.0f);
                }
                *(float4*)&P[(size_t)(pbase + p0 + p) * C3 + ocw] = v;
            }
        }
    }
}

// ---------------------------------------------------------------------------
// Kernel 3: gather-max over the 20 neighbors, one wave per (b,n) row.
// ---------------------------------------------------------------------------
__global__ __launch_bounds__(256) void k_gmax(const float* __restrict__ P,
                                              const int* __restrict__ idx,
                                              float* __restrict__ H) {
    const int t    = threadIdx.x;
    const int lane = t & 63;
    const int bn   = blockIdx.x * 4 + (t >> 6);
    const int b    = bn >> 8;

    const float* Pb = P + (size_t)b * N_ * C3;
    const int*   ib = idx + (size_t)bn * K_;

    float4 m = make_float4(NEG_INF, NEG_INF, NEG_INF, NEG_INF);
    #pragma unroll
    for (int j = 0; j < K_; ++j) {
        const int id = ib[j];
        const float4 p = ((const float4*)(Pb + (size_t)id * C3))[lane];
        m.x = fmaxf(m.x, p.x);
        m.y = fmaxf(m.y, p.y);
        m.z = fmaxf(m.z, p.z);
        m.w = fmaxf(m.w, p.w);
    }
    ((float4*)(H + (size_t)bn * C3))[lane] = m;
}

// ---------------------------------------------------------------------------
// Kernel 4: fused fc1(relu)+fc2. Block = (b, 16-channel tile), 128 threads.
// fc1: tile 8j x 8ch, n split in quarters (merged shfl_xor(32) + LDS handoff).
// fc2: tile 5m x 4ch, j split in quarters (same merge pattern).
// ---------------------------------------------------------------------------
__global__ __launch_bounds__(128) void k_fc(const float* __restrict__ H,
                                            const float* __restrict__ fc1w,
                                            const float* __restrict__ fc1b,
                                            const float* __restrict__ fc2w,
                                            const float* __restrict__ fc2b,
                                            float* __restrict__ out) {
    const int b   = blockIdx.x >> 4;
    const int ch0 = (blockIdx.x & 15) * 16;
    const int t   = threadIdx.x;

    __shared__ float Ht[N_ * 16];       // [n][ci], 16 KB
    __shared__ float gl[F1 * 20];       // [j][ci], stride 20 (16B-aligned, depadded banks)
    __shared__ float w2l[F2 * 129];     // [m][j], padded, 20.6 KB
    __shared__ float scr[32 * 64];      // cross-wave merge scratch, 8 KB
    __shared__ float b1l[F1];
    __shared__ float b2l[F2];

    const float* Hb = H + (size_t)b * N_ * C3;
    for (int e = t; e < N_ * 16; e += 128) {
        const int n = e >> 4, ci = e & 15;
        Ht[e] = Hb[(size_t)n * C3 + ch0 + ci];
    }
    for (int e = t; e < F2 * F1; e += 128)
        w2l[(e >> 7) * 129 + (e & 127)] = fc2w[e];
    if (t < F1) b1l[t] = fc1b[t];
    if (t < F2) b2l[t] = fc2b[t];
    __syncthreads();

    // ---- fc1: thread = (jg 0..15, chg 0..1, nh 0..3) ----
    {
        const int j0 = (t & 15) * 8;
        const int c0 = ((t >> 4) & 1) * 8;
        const int nb = (t >> 5) * 64;
        float acc[8][8] = {};
        for (int ng = 0; ng < 16; ++ng) {
            const int n = nb + ng * 4;
            float4 ya[4], yb[4], w[8];
            #pragma unroll
            for (int i = 0; i < 4; ++i) {
                ya[i] = *(const float4*)&Ht[(n + i) * 16 + c0];
                yb[i] = *(const float4*)&Ht[(n + i) * 16 + c0 + 4];
            }
            #pragma unroll
            for (int j = 0; j < 8; ++j) w[j] = *(const float4*)&fc1w[(j0 + j) * N_ + n];
            #pragma unroll
            for (int j = 0; j < 8; ++j) {
                #pragma unroll
                for (int i = 0; i < 4; ++i) {
                    const float wv = (&w[j].x)[i];
                    #pragma unroll
                    for (int c = 0; c < 4; ++c) {
                        acc[j][c]     += wv * (&ya[i].x)[c];
                        acc[j][c + 4] += wv * (&yb[i].x)[c];
                    }
                }
            }
        }
        // merge nh pairs within each wave
        #pragma unroll
        for (int j = 0; j < 8; ++j)
            #pragma unroll
            for (int c = 0; c < 8; ++c)
                acc[j][c] += __shfl_xor(acc[j][c], 32, 64);
        // wave1 lanes 0..31 hand off to wave0
        if (t >= 64 && t < 96) {
            const int s = t & 31;
            #pragma unroll
            for (int j = 0; j < 8; ++j)
                #pragma unroll
                for (int c = 0; c < 8; ++c)
                    scr[s * 64 + j * 8 + c] = acc[j][c];
        }
        __syncthreads();
        if (t < 32) {
            #pragma unroll
            for (int j = 0; j < 8; ++j) {
                const float bj = b1l[j0 + j];
                float4 v0, v1;
                #pragma unroll
                for (int c = 0; c < 4; ++c) {
                    (&v0.x)[c] = fmaxf(acc[j][c]     + scr[t * 64 + j * 8 + c]     + bj, 0.0f);
                    (&v1.x)[c] = fmaxf(acc[j][c + 4] + scr[t * 64 + j * 8 + c + 4] + bj, 0.0f);
                }
                *(float4*)&gl[(j0 + j) * 20 + c0]     = v0;
                *(float4*)&gl[(j0 + j) * 20 + c0 + 4] = v1;
            }
        }
    }
    __syncthreads();

    // ---- fc2: thread = (mg 0..7, cig 0..3, jq 0..3) ----
    {
        const int m0  = (t & 7) * 5;
        const int ci0 = ((t >> 3) & 3) * 4;
        const int jb  = (t >> 5) * 32;
        float a2[5][4] = {};
        for (int j = jb; j < jb + 32; ++j) {
            const float4 y = *(const float4*)&gl[j * 20 + ci0];
            #pragma unroll
            for (int q = 0; q < 5; ++q) {
                const float wv = w2l[(m0 + q) * 129 + j];
                #pragma unroll
                for (int c = 0; c < 4; ++c) a2[q][c] += wv * (&y.x)[c];
            }
        }
        #pragma unroll
        for (int q = 0; q < 5; ++q)
            #pragma unroll
            for (int c = 0; c < 4; ++c)
                a2[q][c] += __shfl_xor(a2[q][c], 32, 64);
        __syncthreads();               // all fc2 reads of w2l/gl done; scr reusable
        if (t >= 64 && t < 96) {
            const int s = t & 31;
            #pragma unroll
            for (int q = 0; q < 5; ++q)
                #pragma unroll
                for (int c = 0; c < 4; ++c)
                    scr[s * 20 + q * 4 + c] = a2[q][c];
        }
        __syncthreads();
        if (t < 32) {
            #pragma unroll
            for (int c = 0; c < 4; ++c) {
                const int ch = ch0 + ci0 + c;
                #pragma unroll
                for (int q = 0; q < 5; ++q) {
                    const float v = a2[q][c] + scr[t * 20 + q * 4 + c] + b2l[m0 + q];
                    out[((size_t)(b * C3 + ch)) * F2 + m0 + q] = v;
                }
            }
        }
    }
}

// ---------------------------------------------------------------------------
extern "C" void kernel_launch(void* const* d_in, const int* in_sizes, int n_in,
                              void* d_out, int out_size, void* d_ws, size_t ws_size,
                              hipStream_t stream) {
    const float* x    = (const float*)d_in[0];
    const float* w1   = (const float*)d_in[1];
    const float* s1   = (const float*)d_in[2];
    const float* t1   = (const float*)d_in[3];
    const float* w2   = (const float*)d_in[4];
    const float* s2   = (const float*)d_in[5];
    const float* t2   = (const float*)d_in[6];
    const float* w3   = (const float*)d_in[7];
    const float* s3   = (const float*)d_in[8];
    const float* t3   = (const float*)d_in[9];
    const float* fc1w = (const float*)d_in[10];
    const float* fc1b = (const float*)d_in[11];
    const float* fc2w = (const float*)d_in[12];
    const float* fc2b = (const float*)d_in[13];
    float* out = (float*)d_out;

    char* ws = (char*)d_ws;
    int*   idx = (int*)ws;
    float* P   = (float*)(ws + (size_t)B_ * N_ * K_ * 4);
    float* H   = P + (size_t)B_ * N_ * C3;

    k_stage1<<<256 + B_ * N_ / 4, 256, 0, stream>>>(x, w1, s1, t1, w2, s2, t2,
                                                    w3, s3, t3, idx, P);
    k_gmax<<<(B_ * N_) / 4, 256, 0, stream>>>(P, idx, H);
    k_fc  <<<B_ * 16, 128, 0, stream>>>(H, fc1w, fc1b, fc2w, fc2b, out);
}